// Round 5
// baseline (193.801 us; speedup 1.0000x reference)
//
#include <hip/hip_runtime.h>

#define SDIM 500
#define DDIM 64
#define NT   256

__device__ __forceinline__ unsigned ford(float x) {
    unsigned u = __float_as_uint(x);
    return u ^ ((unsigned)((int)u >> 31) | 0x80000000u);
}

__device__ __forceinline__ float dot16(float4 a0, float4 a1, float4 a2, float4 a3,
                                       float4 b0, float4 b1, float4 b2, float4 b3) {
    return a0.x*b0.x + a0.y*b0.y + a0.z*b0.z + a0.w*b0.w
         + a1.x*b1.x + a1.y*b1.y + a1.z*b1.z + a1.w*b1.w
         + a2.x*b2.x + a2.y*b2.y + a2.z*b2.z + a2.w*b2.w
         + a3.x*b3.x + a3.y*b3.y + a3.z*b3.z + a3.w*b3.w;
}

// 4 independent waves per 256-thread block, one row per wave, NO __syncthreads.
// Each wave owns private LDS slices; intra-wave DS ops execute in order, so
// wave_barrier() (compiler fence, zero HW cost) is enough between phases.
__global__ __launch_bounds__(NT, 6) void rs_main(
    const int* __restrict__ need_replace,    // (N,2)
    const float* __restrict__ union_feature, // (N,128)
    const float* __restrict__ all_items,     // (n_items,64)
    const int* __restrict__ sample_items,    // (n_users,500)
    const float* __restrict__ Wm,            // (64,128)
    const float* __restrict__ bv,            // (64)
    const float* __restrict__ gumbel_u,      // (N,500)
    float* __restrict__ out_items,           // (N)
    float* __restrict__ out_feat,            // (N,64)
    int* __restrict__ ws_acc)                // [0]=sum(pos), [1]=sum|pos-250|
{
    __shared__ unsigned s_fv_all[4][SDIM];
    __shared__ int      s_hist_all[4][256];
    __shared__ __align__(16) float s_uif_all[4][DDIM];

    const int wid  = threadIdx.x >> 6;
    const int lane = threadIdx.x & 63;
    const int part = lane & 3, quad = lane >> 2;
    const int n    = blockIdx.x * 4 + wid;

    unsigned* s_fv   = s_fv_all[wid];
    int*      s_hist = s_hist_all[wid];
    float*    s_uif  = s_uif_all[wid];

    const int user = need_replace[2 * n];
    const int item = need_replace[2 * n + 1];
    const int*   samp = sample_items + (long)user * SDIM;
    const float* gur  = gumbel_u + (long)n * SDIM;

    // item-embedding fragment: 16 floats per lane, selected by part
    const float4* ir = (const float4*)(all_items + (long)item * DDIM) + part * 4;
    const float4 wiA = ir[0], wiB = ir[1], wiC = ir[2], wiD = ir[3];

    // ---- uif = W @ uf + b : quad q computes rows q, q+16, q+32, q+48 ----
    {
        const float4* ufr = (const float4*)(union_feature + (long)n * 128) + part * 8;
        float4 u0 = ufr[0], u1 = ufr[1], u2 = ufr[2], u3 = ufr[3];
        float4 u4 = ufr[4], u5 = ufr[5], u6 = ufr[6], u7 = ufr[7];
        #pragma unroll
        for (int r = 0; r < 4; ++r) {
            const int row = quad + 16 * r;
            const float4* wr = (const float4*)(Wm + (long)row * 128) + part * 8;
            float4 w0 = wr[0], w1 = wr[1], w2 = wr[2], w3 = wr[3];
            float4 w4 = wr[4], w5 = wr[5], w6 = wr[6], w7 = wr[7];
            float acc = dot16(w0, w1, w2, w3, u0, u1, u2, u3)
                      + dot16(w4, w5, w6, w7, u4, u5, u6, u7);
            acc += __shfl_xor(acc, 1);
            acc += __shfl_xor(acc, 2);
            if (part == 0) s_uif[row] = acc + bv[row];
        }
    }
    __builtin_amdgcn_wave_barrier();
    const float4* ur = (const float4*)s_uif + part * 4;
    const float4 wuA = ur[0], wuB = ur[1], wuC = ur[2], wuD = ur[3];

    // ---- score phase: quad per sample row, fused gumbel + argmax ----
    float bvv = -__builtin_inff();
    int   bii = SDIM;
    #pragma unroll 4
    for (int i = 0; i < 32; ++i) {
        const int s = i * 16 + quad;
        const bool act = (s < SDIM);
        const int sc = act ? s : 0;
        const int idx = samp[sc];
        const float4* fr = (const float4*)(all_items + (long)idx * DDIM) + part * 4;
        float4 f0 = fr[0], f1 = fr[1], f2 = fr[2], f3 = fr[3];
        float a0 = dot16(f0, f1, f2, f3, wiA, wiB, wiC, wiD);
        float a1 = dot16(f0, f1, f2, f3, wuA, wuB, wuC, wuD);
        a0 += __shfl_xor(a0, 1); a0 += __shfl_xor(a0, 2);
        a1 += __shfl_xor(a1, 1); a1 += __shfl_xor(a1, 2);
        float u = gur[sc];
        float g = -logf(-logf(u * (1.0f - 2e-7f) + 1e-7f));
        float v = a1 + g;
        if (act) {
            if (v > bvv) { bvv = v; bii = s; }   // ascending s keeps first max
            if (part == 0) s_fv[s] = ford(a0);
        }
    }
    // wave argmax, first-index tie-break (matches jnp.argmax)
    #pragma unroll
    for (int off = 1; off < 64; off <<= 1) {
        float v2 = __shfl_xor(bvv, off);
        int   i2 = __shfl_xor(bii, off);
        if (v2 > bvv || (v2 == bvv && i2 < bii)) { bvv = v2; bii = i2; }
    }
    const int k = bii;
    __builtin_amdgcn_wave_barrier();

    // ---- rank_k = stable rank of element k ----
    int rank_k = 0;
    {
        const unsigned fvk = s_fv[k];
        for (int s = lane; s < SDIM; s += 64) {
            unsigned v = s_fv[s];
            rank_k += (int)((v < fvk) | ((v == fvk) & (s < k)));
        }
        #pragma unroll
        for (int off = 1; off < 64; off <<= 1) rank_k += __shfl_xor(rank_k, off);
    }

    // ---- radix-select: j* = index of k-th smallest (stable) ----
    unsigned prefix = 0;
    int krem = k;
    #pragma unroll
    for (int pass = 0; pass < 4; ++pass) {
        const int shift = 24 - 8 * pass;
        s_hist[lane] = 0; s_hist[lane + 64] = 0; s_hist[lane + 128] = 0; s_hist[lane + 192] = 0;
        __builtin_amdgcn_wave_barrier();
        const unsigned himask = pass ? (0xFFFFFFFFu << (shift + 8)) : 0u;
        for (int s = lane; s < SDIM; s += 64) {
            unsigned v = s_fv[s];
            if ((v & himask) == prefix) atomicAdd(&s_hist[(v >> shift) & 0xFF], 1);
        }
        __builtin_amdgcn_wave_barrier();
        int h0 = s_hist[4 * lane], h1 = s_hist[4 * lane + 1];
        int h2 = s_hist[4 * lane + 2], h3 = s_hist[4 * lane + 3];
        int s4 = h0 + h1 + h2 + h3, inc = s4;
        #pragma unroll
        for (int off = 1; off < 64; off <<= 1) {
            int t = __shfl_up(inc, off);
            if (lane >= off) inc += t;
        }
        const int base = inc - s4;
        const bool found = (krem >= base) && (krem < inc);
        int selb = 0, selk = 0;
        if (found) {
            if      (krem < base + h0)           { selb = 4 * lane;     selk = krem - base; }
            else if (krem < base + h0 + h1)      { selb = 4 * lane + 1; selk = krem - base - h0; }
            else if (krem < base + h0 + h1 + h2) { selb = 4 * lane + 2; selk = krem - base - h0 - h1; }
            else                                 { selb = 4 * lane + 3; selk = krem - base - h0 - h1 - h2; }
        }
        unsigned long long m = __ballot(found);
        int srcl = __ffsll((long long)m) - 1;
        selb = __shfl(selb, srcl);
        selk = __shfl(selk, srcl);
        prefix |= ((unsigned)selb) << shift;
        krem = selk;
        __builtin_amdgcn_wave_barrier();
    }

    // ---- stable tie resolution among fv==prefix by original index ----
    int jstar = -1;
    {
        int basec = 0;
        #pragma unroll
        for (int c = 0; c < 8; ++c) {
            const int s = c * 64 + lane;
            const bool m = (s < SDIM) && (s_fv[s] == prefix);
            unsigned long long mask = __ballot(m);
            int myrank = __popcll(mask & ((1ull << lane) - 1ull));
            if (m && (basec + myrank == krem)) jstar = s;
            basec += __popcll(mask);
        }
        unsigned long long mm = __ballot(jstar >= 0);
        int srcl = __ffsll((long long)mm) - 1;
        jstar = __shfl(jstar, srcl);
    }

    // ---- outputs ----
    const int src_item = samp[k];
    out_feat[(long)n * DDIM + lane] = all_items[(long)src_item * DDIM + lane];
    if (lane == 0) {
        out_items[n] = (float)samp[jstar];
        const int pos = rank_k + 1;                 // similarity = pos/500
        atomicAdd(&ws_acc[0], pos);                 // for mean(similarity)
        atomicAdd(&ws_acc[1], abs(pos - 250));      // |sim-0.5| = |pos-250|/500
    }
}

__global__ __launch_bounds__(64) void rs_fin(const int* __restrict__ ws_acc,
                                             float* __restrict__ out_scal, int N)
{
    if (threadIdx.x == 0) {
        const double denom = (double)SDIM * (double)N;
        out_scal[0] = (float)((double)ws_acc[1] / denom);  // similarity_loss
        out_scal[1] = (float)((double)ws_acc[0] / denom);  // mean(similarity)
    }
}

extern "C" void kernel_launch(void* const* d_in, const int* in_sizes, int n_in,
                              void* d_out, int out_size, void* d_ws, size_t ws_size,
                              hipStream_t stream) {
    const int*   need_replace  = (const int*)d_in[0];
    const float* union_feature = (const float*)d_in[1];
    const float* all_items     = (const float*)d_in[2];
    const int*   sample_items  = (const int*)d_in[3];
    const float* Wm            = (const float*)d_in[4];
    const float* bv            = (const float*)d_in[5];
    const float* gumbel_u      = (const float*)d_in[6];

    const int N = in_sizes[0] / 2;  // 4096

    float* out       = (float*)d_out;
    float* out_items = out;                       // N
    float* out_feat  = out + N;                   // N*64
    float* out_scal  = out + N + (long)N * DDIM;  // 2 scalars
    int*   ws_acc    = (int*)d_ws;                // 2 ints

    hipMemsetAsync(ws_acc, 0, 2 * sizeof(int), stream);
    rs_main<<<N / 4, NT, 0, stream>>>(need_replace, union_feature, all_items,
                                      sample_items, Wm, bv, gumbel_u,
                                      out_items, out_feat, ws_acc);
    rs_fin<<<1, 64, 0, stream>>>(ws_acc, out_scal, N);
}

// Round 6
// 136.280 us; speedup vs baseline: 1.4221x; 1.4221x over previous
//
#include <hip/hip_runtime.h>

#define SDIM 500
#define DDIM 64
#define NT   256
#define HBITS  11
#define HBINS  (1 << HBITS)    // 2048
#define HSHIFT (32 - HBITS)    // 21

__device__ __forceinline__ unsigned ford(float x) {
    unsigned u = __float_as_uint(x);
    return u ^ ((unsigned)((int)u >> 31) | 0x80000000u);
}

__device__ __forceinline__ float dot16(float4 a0, float4 a1, float4 a2, float4 a3,
                                       float4 b0, float4 b1, float4 b2, float4 b3) {
    return a0.x*b0.x + a0.y*b0.y + a0.z*b0.z + a0.w*b0.w
         + a1.x*b1.x + a1.y*b1.y + a1.z*b1.z + a1.w*b1.w
         + a2.x*b2.x + a2.y*b2.y + a2.z*b2.z + a2.w*b2.w
         + a3.x*b3.x + a3.y*b3.y + a3.z*b3.z + a3.w*b3.w;
}

// One row per 256-thread block (4 waves cooperate => 16384 waves total for
// latency hiding). Score gathers are depth-1 software-pipelined; selection is
// one 11-bit histogram + candidate compaction + direct stable ranking.
__global__ __launch_bounds__(NT, 6) void rs_main(
    const int* __restrict__ need_replace,    // (N,2)
    const float* __restrict__ union_feature, // (N,128)
    const float* __restrict__ all_items,     // (n_items,64)
    const int* __restrict__ sample_items,    // (n_users,500)
    const float* __restrict__ Wm,            // (64,128)
    const float* __restrict__ bv,            // (64)
    const float* __restrict__ gumbel_u,      // (N,500)
    float* __restrict__ out_items,           // (N)
    float* __restrict__ out_feat,            // (N,64)
    int* __restrict__ ws_acc)                // [0]=sum(pos), [1]=sum|pos-250|
{
    __shared__ __align__(16) float s_uf[128];
    __shared__ __align__(16) float s_uif[DDIM];
    __shared__ unsigned s_fv[SDIM];
    __shared__ float    s_key[SDIM];
    __shared__ int      s_samp[SDIM];
    __shared__ union {
        int hist[HBINS];                       // 8 KB, dead after bucket pick
        unsigned long long cand[SDIM];         // 4 KB, lives after
    } s_u;
    __shared__ float s_mv[4];
    __shared__ int   s_mi[4];
    __shared__ int   s_cnt4[4];
    __shared__ int   s_wt[4];
    __shared__ int   s_k, s_selb, s_base, s_cn, s_jstar;

    const int n    = blockIdx.x;
    const int tid  = threadIdx.x;
    const int wid  = tid >> 6;
    const int lane = tid & 63;
    const int part = tid & 3, quad = tid >> 2;

    const int user = need_replace[2 * n];
    const int item = need_replace[2 * n + 1];
    const int*   samp_row = sample_items + (long)user * SDIM;
    const float* gur      = gumbel_u + (long)n * SDIM;

    // ---- stage (coalesced) ----
    if (tid < 128) s_uf[tid] = union_feature[(long)n * 128 + tid];
    for (int s = tid; s < SDIM; s += NT) s_samp[s] = samp_row[s];
    // item-embedding fragment (16 floats/lane by part; L1-broadcast across quads)
    const float4* ir = (const float4*)(all_items + (long)item * DDIM) + part * 4;
    const float4 wiA = ir[0], wiB = ir[1], wiC = ir[2], wiD = ir[3];
    __syncthreads();

    // ---- uif = W @ uf + b : 4 lanes per output row ----
    {
        const int row = quad;            // 0..63
        const float4* wr4 = (const float4*)(Wm + (long)row * 128);
        const float4* uf4 = (const float4*)s_uf;
        float acc = 0.f;
        #pragma unroll
        for (int q = 0; q < 8; ++q) {
            float4 w4 = wr4[part + q * 4];
            float4 u4 = uf4[part + q * 4];
            acc += w4.x * u4.x + w4.y * u4.y + w4.z * u4.z + w4.w * u4.w;
        }
        acc += __shfl_xor(acc, 1);
        acc += __shfl_xor(acc, 2);
        if (part == 0) s_uif[row] = acc + bv[row];
    }
    __syncthreads();
    const float4* ur = (const float4*)s_uif + part * 4;
    const float4 wuA = ur[0], wuB = ur[1], wuC = ur[2], wuD = ur[3];

    // ---- score loop: quad per sample, depth-1 prefetched gathers ----
    float4 f0, f1, f2, f3;
    {
        const int idx0 = s_samp[quad];   // s = quad < 64 always valid
        const float4* p = (const float4*)(all_items + (long)idx0 * DDIM) + part * 4;
        f0 = p[0]; f1 = p[1]; f2 = p[2]; f3 = p[3];
    }
    #pragma unroll
    for (int i = 0; i < 8; ++i) {
        const int s = i * 64 + quad;
        float4 g0 = f0, g1 = f1, g2 = f2, g3 = f3;
        if (i < 7) {
            const int sn = s + 64;
            const bool actn = (sn < SDIM);
            const int idxn = s_samp[actn ? sn : 0];
            const float4* q = (const float4*)(all_items + (long)idxn * DDIM) + part * 4;
            if (actn) { g0 = q[0]; g1 = q[1]; g2 = q[2]; g3 = q[3]; }
        }
        const bool act = (s < SDIM);
        float a0 = dot16(f0, f1, f2, f3, wiA, wiB, wiC, wiD);
        float a1 = dot16(f0, f1, f2, f3, wuA, wuB, wuC, wuD);
        a0 += __shfl_xor(a0, 1); a0 += __shfl_xor(a0, 2);
        a1 += __shfl_xor(a1, 1); a1 += __shfl_xor(a1, 2);
        if (act && part == 0) { s_fv[s] = ford(a0); s_key[s] = a1; }
        f0 = g0; f1 = g1; f2 = g2; f3 = g3;
    }
    __syncthreads();

    // ---- argmax of replace_score + gumbel (first-max tie-break) ----
    {
        float bvv = -__builtin_inff();
        int   bii = SDIM;
        for (int s = tid; s < SDIM; s += NT) {
            float u = gur[s];
            float g = -logf(-logf(u * (1.0f - 2e-7f) + 1e-7f));
            float v = s_key[s] + g;
            if (v > bvv) { bvv = v; bii = s; }
        }
        #pragma unroll
        for (int off = 1; off < 64; off <<= 1) {
            float v2 = __shfl_xor(bvv, off); int i2 = __shfl_xor(bii, off);
            if (v2 > bvv || (v2 == bvv && i2 < bii)) { bvv = v2; bii = i2; }
        }
        if (lane == 0) { s_mv[wid] = bvv; s_mi[wid] = bii; }
        __syncthreads();
        if (tid == 0) {
            float mv = s_mv[0]; int mi = s_mi[0];
            #pragma unroll
            for (int w = 1; w < 4; ++w) {
                float v2 = s_mv[w]; int i2 = s_mi[w];
                if (v2 > mv || (v2 == mv && i2 < mi)) { mv = v2; mi = i2; }
            }
            s_k = mi;
        }
        __syncthreads();
    }
    const int k = s_k;

    // ---- overlap: feature output = all_items[samp[k]] ----
    {
        const int src = s_samp[k];
        if (tid < DDIM)
            out_feat[(long)n * DDIM + tid] = all_items[(long)src * DDIM + tid];
    }

    // ---- fused pass: rank_k count + 11-bit histogram ----
    for (int h = tid; h < HBINS; h += NT) s_u.hist[h] = 0;
    __syncthreads();
    const unsigned fvk = s_fv[k];
    {
        int cnt = 0;
        for (int s = tid; s < SDIM; s += NT) {
            unsigned v = s_fv[s];
            cnt += (int)((v < fvk) | ((v == fvk) & (s < k)));
            atomicAdd(&s_u.hist[v >> HSHIFT], 1);
        }
        #pragma unroll
        for (int off = 1; off < 64; off <<= 1) cnt += __shfl_xor(cnt, off);
        if (lane == 0) s_cnt4[wid] = cnt;
    }
    __syncthreads();
    const int rank_k = s_cnt4[0] + s_cnt4[1] + s_cnt4[2] + s_cnt4[3];

    // ---- block scan over 2048 bins; locate bucket containing k-th smallest ----
    {
        int b[8]; int p = 0;
        #pragma unroll
        for (int j = 0; j < 8; ++j) { b[j] = s_u.hist[tid * 8 + j]; p += b[j]; }
        int inc = p;
        #pragma unroll
        for (int off = 1; off < 64; off <<= 1) {
            int t = __shfl_up(inc, off);
            if (lane >= off) inc += t;
        }
        if (lane == 63) s_wt[wid] = inc;
        __syncthreads();
        int wbase = 0;
        for (int w = 0; w < wid; ++w) wbase += s_wt[w];
        int run = wbase + inc - p;           // exclusive prefix of this thread's bins
        #pragma unroll
        for (int j = 0; j < 8; ++j) {
            if (k >= run && k < run + b[j]) { s_selb = tid * 8 + j; s_base = run; }
            run += b[j];
        }
    }
    __syncthreads();
    const int selb = s_selb;
    const int kb   = k - s_base;     // rank within bucket
    __syncthreads();                 // all reads of hist done -> reuse as cand
    if (tid == 0) { s_cn = 0; s_jstar = -1; }
    __syncthreads();

    // ---- compact candidates of the selected bucket ----
    for (int s = tid; s < SDIM; s += NT) {
        unsigned v = s_fv[s];
        if ((int)(v >> HSHIFT) == selb) {
            int slot = atomicAdd(&s_cn, 1);
            s_u.cand[slot] = ((unsigned long long)v << 32) | (unsigned)s;
        }
    }
    __syncthreads();
    const int C = s_cn;

    // ---- stable ranking among candidates (64-bit keys: fv then index) ----
    for (int i = tid; i < C; i += NT) {
        unsigned long long w = s_u.cand[i];
        int r = 0;
        for (int j = 0; j < C; ++j) r += (int)(s_u.cand[j] < w);
        if (r == kb) s_jstar = (int)(w & 0xffffffffu);
    }
    __syncthreads();

    // ---- outputs ----
    if (tid == 0) {
        out_items[n] = (float)s_samp[s_jstar];
        const int pos = rank_k + 1;            // similarity = pos/500
        atomicAdd(&ws_acc[0], pos);            // mean(similarity)
        atomicAdd(&ws_acc[1], abs(pos - 250)); // |sim-0.5| = |pos-250|/500
    }
}

__global__ __launch_bounds__(64) void rs_fin(const int* __restrict__ ws_acc,
                                             float* __restrict__ out_scal, int N)
{
    if (threadIdx.x == 0) {
        const double denom = (double)SDIM * (double)N;
        out_scal[0] = (float)((double)ws_acc[1] / denom);  // similarity_loss
        out_scal[1] = (float)((double)ws_acc[0] / denom);  // mean(similarity)
    }
}

extern "C" void kernel_launch(void* const* d_in, const int* in_sizes, int n_in,
                              void* d_out, int out_size, void* d_ws, size_t ws_size,
                              hipStream_t stream) {
    const int*   need_replace  = (const int*)d_in[0];
    const float* union_feature = (const float*)d_in[1];
    const float* all_items     = (const float*)d_in[2];
    const int*   sample_items  = (const int*)d_in[3];
    const float* Wm            = (const float*)d_in[4];
    const float* bv            = (const float*)d_in[5];
    const float* gumbel_u      = (const float*)d_in[6];

    const int N = in_sizes[0] / 2;  // 4096

    float* out       = (float*)d_out;
    float* out_items = out;                       // N
    float* out_feat  = out + N;                   // N*64
    float* out_scal  = out + N + (long)N * DDIM;  // 2 scalars
    int*   ws_acc    = (int*)d_ws;                // 2 ints

    hipMemsetAsync(ws_acc, 0, 2 * sizeof(int), stream);
    rs_main<<<N, NT, 0, stream>>>(need_replace, union_feature, all_items,
                                  sample_items, Wm, bv, gumbel_u,
                                  out_items, out_feat, ws_acc);
    rs_fin<<<1, 64, 0, stream>>>(ws_acc, out_scal, N);
}